// Round 8
// baseline (285.517 us; speedup 1.0000x reference)
//
#include <hip/hip_runtime.h>

// Butterfly network: 12 stages over rows of 4096 fp32.
// y[p] <- W[s][p][0]*y[p] + W[s][p][1]*y[p^d],  d = 1<<s, s = 0..11
//
// ROUND 8 REDESIGN: cross-lane butterflies. In layout L1 (p = 8t+i, t=thread,
// i=reg slot), stage-s partners for s=3..8 differ only in LANE bits
// (p^d, d=8..256  <=>  lane^1..lane^32). So stages 3..8 need NO LDS
// round-trip: fetch the partner value with ds_swizzle (xor 1,2,4,8,16) /
// ds_bpermute (xor 32) and apply the uniform butterfly
//     v_new[p] = W[p].x * v[p] + W[p].y * v[p^d]
// (reference: W[s][p][0] scales y[p], W[s][p][1] scales y[p^d], both sides).
// Weights for s=0..8 are CONTIGUOUS per thread (16 floats at 8t) -> all
// coalesced dwordx4. Rounds 4-7 showed waves stalled ~97% of their life on
// transition machinery (4 full lgkmcnt(0) drains + 3 barriers + 96 LDS ops
// per group); this structure has ONE barrier and 16 LDS memory ops total.
//
//   stages 0..2 : in-register (reg-index bits of i)
//   stages 3..8 : cross-lane (ds_swizzle xor1,2,4,8,16; ds_bpermute xor32)
//   transition  : L1 (p=8t+i) -> L4 (p=512k+t), float4-packed (4 rows),
//                 8 ds_write_b128 + __syncthreads + 8 ds_read_b128
//   stages 9..11: in-register (reg-index bits of k) + coalesced store
//
// Transition swizzle: slot' = slot ^ ((slot>>6)&7)  (involution, bijective).
//   write (fixed i): slot=8t+i -> bank-group = i ^ t[5:3] -> 8 groups even ✓
//   read (fixed k): slot=512k+t -> bank-group = t[2:0] ^ t6 -> 8 groups even ✓
//   both sides at the b128 floor (8 lanes/cycle), conflict-free.
//
// Allocator law (R1-3,6,7): backend targets LDS-implied occupancy and
// squeezes VGPRs to it. LDS = 64 KB exactly -> 2 blocks/CU -> 4 waves/SIMD
// target -> 128-reg budget >> natural ~75 -> no spill.
// Spill tripwire: WRITE_SIZE must be exactly 131072 KB.

constexpr int LROW = 4096;
constexpr int RPB  = 4;              // rows per block
constexpr int NBLK = 8192 / RPB;     // 2048 blocks x 512 threads

__device__ __forceinline__ int swz(int s) { return s ^ ((s >> 6) & 7); }

// cross-lane fetch of the partner value (lane ^ D)
template<int D>
__device__ __forceinline__ float xl(float x, int bpa) {
    const int xi = __builtin_bit_cast(int, x);
    int r;
    if      constexpr (D == 1)  r = __builtin_amdgcn_ds_swizzle(xi, 0x041F); // xor1
    else if constexpr (D == 2)  r = __builtin_amdgcn_ds_swizzle(xi, 0x081F); // xor2
    else if constexpr (D == 4)  r = __builtin_amdgcn_ds_swizzle(xi, 0x101F); // xor4
    else if constexpr (D == 8)  r = __builtin_amdgcn_ds_swizzle(xi, 0x201F); // xor8
    else if constexpr (D == 16) r = __builtin_amdgcn_ds_swizzle(xi, 0x401F); // xor16
    else                        r = __builtin_amdgcn_ds_bpermute(bpa, xi);   // xor32
    return __builtin_bit_cast(float, r);
}

// contiguous weight load (valid for stages 0..8): 16 floats at position 8t
template<int S>
__device__ __forceinline__ void loadA(float2 (&w)[8], const float* __restrict__ W, int t) {
    const float4* q4 = reinterpret_cast<const float4*>(W + (size_t)S * 8192 + 16 * t);
    #pragma unroll
    for (int m = 0; m < 4; ++m) {
        const float4 q = q4[m];
        w[2*m]   = make_float2(q.x, q.y);
        w[2*m+1] = make_float2(q.z, q.w);
    }
}

// strided weight load for stages 9..11: positions 512k + t
template<int S>
__device__ __forceinline__ void loadD(float2 (&w)[8], const float* __restrict__ W, int t) {
    const float2* q2 = reinterpret_cast<const float2*>(W) + (size_t)S * 4096 + t;
    #pragma unroll
    for (int m = 0; m < 8; ++m) w[m] = q2[m * 512];
}

// in-register butterfly stage over reg-index distance DL
template<int DL>
__device__ __forceinline__ void rstage(float (&v)[RPB][8], const float2 (&w)[8]) {
    #pragma unroll
    for (int g = 0; g < 8; g += 2*DL)
        #pragma unroll
        for (int m = 0; m < DL; ++m) {
            const int a = g + m, c = a + DL;
            #pragma unroll
            for (int r = 0; r < RPB; ++r) {
                const float va = v[r][a], vb = v[r][c];
                v[r][a] = w[a].x * va + w[a].y * vb;
                v[r][c] = w[c].x * vb + w[c].y * va;
            }
        }
}

// cross-lane butterfly stage: partner = lane ^ D, uniform form
template<int S, int D>
__device__ __forceinline__ void xstage(float (&v)[RPB][8], const float* __restrict__ W,
                                       int t, int bpa) {
    float2 w[8];
    loadA<S>(w, W, t);
    #pragma unroll
    for (int r = 0; r < RPB; ++r) {
        float u[8];
        #pragma unroll
        for (int i = 0; i < 8; ++i) u[i] = xl<D>(v[r][i], bpa);
        #pragma unroll
        for (int i = 0; i < 8; ++i) v[r][i] = w[i].x * v[r][i] + w[i].y * u[i];
    }
}

__global__ __launch_bounds__(512)
void butterfly12_kernel(const float* __restrict__ x,
                        const float* __restrict__ W,
                        float* __restrict__ out)
{
    __shared__ float4 lds4[4096];   // 64 KB exactly -> 2 blocks/CU

    const int t   = threadIdx.x;                 // 9 bits
    const int bpa = ((t & 63) ^ 32) << 2;        // ds_bpermute addr: lane^32
    const size_t row0 = (size_t)blockIdx.x * RPB;

    float v[RPB][8];

    // ---- load x: L1, p = 8t + i, 2 x dwordx4 per row, coalesced ----
    #pragma unroll
    for (int r = 0; r < RPB; ++r) {
        const float4* xr = reinterpret_cast<const float4*>(x + (row0 + r) * LROW + 8 * t);
        const float4 qa = xr[0], qb = xr[1];
        v[r][0]=qa.x; v[r][1]=qa.y; v[r][2]=qa.z; v[r][3]=qa.w;
        v[r][4]=qb.x; v[r][5]=qb.y; v[r][6]=qb.z; v[r][7]=qb.w;
    }

    // ---- stages 0..2: in-register (p bits 0-2 = reg index i) ----
    { float2 w[8]; loadA<0>(w, W, t); rstage<1>(v, w); }
    { float2 w[8]; loadA<1>(w, W, t); rstage<2>(v, w); }
    { float2 w[8]; loadA<2>(w, W, t); rstage<4>(v, w); }

    // ---- stages 3..8: cross-lane (p bits 3-8 = lane bits 0-5) ----
    xstage<3, 1 >(v, W, t, bpa);
    xstage<4, 2 >(v, W, t, bpa);
    xstage<5, 4 >(v, W, t, bpa);
    xstage<6, 8 >(v, W, t, bpa);
    xstage<7, 16>(v, W, t, bpa);
    xstage<8, 32>(v, W, t, bpa);

    // ---- transition: L1 (p = 8t+i) -> L4 (p = 512k + t), float4 = 4 rows ----
    #pragma unroll
    for (int i = 0; i < 8; ++i)
        lds4[swz(8*t + i)] = make_float4(v[0][i], v[1][i], v[2][i], v[3][i]);
    __syncthreads();
    #pragma unroll
    for (int k = 0; k < 8; ++k) {
        const float4 q = lds4[swz(512*k + t)];
        v[0][k] = q.x; v[1][k] = q.y; v[2][k] = q.z; v[3][k] = q.w;
    }

    // ---- stages 9..11: in-register (p bits 9-11 = reg index k) ----
    { float2 w[8]; loadD<9 >(w, W, t); rstage<1>(v, w); }
    { float2 w[8]; loadD<10>(w, W, t); rstage<2>(v, w); }
    { float2 w[8]; loadD<11>(w, W, t); rstage<4>(v, w); }

    // ---- store: L4, p = 512k + t => fully coalesced ----
    #pragma unroll
    for (int r = 0; r < RPB; ++r) {
        float* orow = out + (row0 + r) * LROW;
        #pragma unroll
        for (int k = 0; k < 8; ++k)
            orow[k*512 + t] = v[r][k];
    }
}

extern "C" void kernel_launch(void* const* d_in, const int* in_sizes, int n_in,
                              void* d_out, int out_size, void* d_ws, size_t ws_size,
                              hipStream_t stream) {
    const float* x = (const float*)d_in[0];   // (8192, 4096) fp32
    const float* W = (const float*)d_in[1];   // (12, 4096, 2) fp32
    float* out = (float*)d_out;               // (8192, 4096) fp32

    butterfly12_kernel<<<NBLK, 512, 0, stream>>>(x, W, out);
}